// Round 9
// baseline (1498.878 us; speedup 1.0000x reference)
//
#include <hip/hip_runtime.h>
#include <hip/hip_fp16.h>

#define LATENT 64
#define N_USERS_C 100000

#define BROWS 128              // rows per bucket
#define LOG_BROWS 7
#define NBUCK_MAX 1280         // >= ceil(150000/128)=1172
#define SORT_T 256
#define SORT_E 16
#define SORT_CHUNK (SORT_T * SORT_E)   // 4096 edges per block
#define ACC_STRIDE 68          // 64 + 4 pad: spreads LDS atomic banks across rows

// ---------- bucket histogram (LDS pre-reduced) ----------

__global__ void bhist_kernel(const int* __restrict__ row, int* __restrict__ bcnt,
                             int nnz, int nbuck) {
    __shared__ int cnt[NBUCK_MAX];
    for (int i = threadIdx.x; i < nbuck; i += SORT_T) cnt[i] = 0;
    __syncthreads();
    int base = blockIdx.x * SORT_CHUNK;
#pragma unroll
    for (int j = 0; j < SORT_E; j++) {
        int e = base + j * SORT_T + threadIdx.x;
        if (e < nnz) atomicAdd(&cnt[row[e] >> LOG_BROWS], 1);
    }
    __syncthreads();
    for (int i = threadIdx.x; i < nbuck; i += SORT_T)
        if (cnt[i]) atomicAdd(&bcnt[i], cnt[i]);
}

// ---------- bucket exclusive scan (single block; nbuck ~1172) ----------

__global__ void bscan_kernel(const int* __restrict__ bcnt, int* __restrict__ bstart,
                             int* __restrict__ bcur, int nbuck) {
    __shared__ int part[SORT_T];
    int t = threadIdx.x;
    int chunk = (nbuck + SORT_T - 1) / SORT_T;
    int lo = t * chunk;
    int hi = lo + chunk; if (hi > nbuck) hi = nbuck;
    int s = 0;
    for (int i = lo; i < hi; i++) s += bcnt[i];
    part[t] = s;
    __syncthreads();
    for (int o = 1; o < SORT_T; o <<= 1) {
        int x = (t >= o) ? part[t - o] : 0;
        __syncthreads();
        part[t] += x;
        __syncthreads();
    }
    int run = (t == 0) ? 0 : part[t - 1];
    for (int i = lo; i < hi; i++) { bstart[i] = run; bcur[i] = run; run += bcnt[i]; }
    if (t == SORT_T - 1) bstart[nbuck] = run;   // total = nnz
}

// ---------- LDS counting sort of edges into bucket-grouped order ----------
// Payload: .x = col | (rowLocal<<18)  (col<2^18, rowLocal<128), .y = val bits.
// Per-bucket contiguous runs are written out by one thread each (~3.5 edges),
// replacing the fully-random 8B scatter (R7: 75MB WRITE for 9.6MB payload).

__global__ void sort_kernel(const int* __restrict__ row, const int* __restrict__ col,
                            const float* __restrict__ vals, int* __restrict__ bcur,
                            uint2* __restrict__ edgesOut, int nnz, int nbuck) {
    __shared__ int cnt[NBUCK_MAX];
    __shared__ int off[NBUCK_MAX];
    __shared__ int part[SORT_T];
    __shared__ uint2 buf[SORT_CHUNK];   // 32 KB
    int t = threadIdx.x;
    int base = blockIdx.x * SORT_CHUNK;

    for (int i = t; i < nbuck; i += SORT_T) cnt[i] = 0;
    __syncthreads();

    int   eb[SORT_E];
    uint2 pl[SORT_E];
#pragma unroll
    for (int j = 0; j < SORT_E; j++) {
        int e = base + j * SORT_T + t;
        if (e < nnz) {
            int r = row[e];
            int b = r >> LOG_BROWS;
            eb[j] = b;
            pl[j] = make_uint2((unsigned)col[e] | ((unsigned)(r & (BROWS - 1)) << 18),
                               (unsigned)__float_as_int(vals[e]));
            atomicAdd(&cnt[b], 1);
        } else {
            eb[j] = -1;
        }
    }
    __syncthreads();

    // exclusive scan cnt -> off
    int chunk = (nbuck + SORT_T - 1) / SORT_T;
    int lo = t * chunk;
    int hi = lo + chunk; if (hi > nbuck) hi = nbuck;
    int s = 0;
    for (int i = lo; i < hi; i++) s += cnt[i];
    part[t] = s;
    __syncthreads();
    for (int o = 1; o < SORT_T; o <<= 1) {
        int x = (t >= o) ? part[t - o] : 0;
        __syncthreads();
        part[t] += x;
        __syncthreads();
    }
    int run = (t == 0) ? 0 : part[t - 1];
    for (int i = lo; i < hi; i++) { off[i] = run; run += cnt[i]; }
    __syncthreads();

    // place into LDS buffer (bucket-grouped)
#pragma unroll
    for (int j = 0; j < SORT_E; j++) {
        if (eb[j] >= 0) {
            int p = atomicAdd(&off[eb[j]], 1);
            buf[p] = pl[j];
        }
    }
    __syncthreads();

    // write out per-bucket contiguous runs (off[b] is now end-of-bucket)
    for (int b = t; b < nbuck; b += SORT_T) {
        int c = cnt[b];
        if (c) {
            int end = off[b];
            int beg = end - c;
            int g = atomicAdd(&bcur[b], c);
            for (int i = 0; i < c; i++) edgesOut[g + i] = buf[beg + i];
        }
    }
}

// fp32 -> fp16 table conversion, 4 elements/thread.
__global__ void conv_kernel(const float* __restrict__ in, __half* __restrict__ outh, int n4) {
    int i = blockIdx.x * blockDim.x + threadIdx.x;
    if (i >= n4) return;
    float4 v = ((const float4*)in)[i];
    __half2* o = (__half2*)outh;
    o[2 * i]     = __floats2half2_rn(v.x, v.y);
    o[2 * i + 1] = __floats2half2_rn(v.z, v.w);
}

// ---------- Bucket SpMM: one block per 128-row bucket ----------
// fp32 LDS accumulator (stride 68 spreads atomic banks). Edges streamed
// densely: wave takes 16 consecutive edges/iter, 4 lane-groups of 16 own 4
// edges per gather instruction (ushort4 = 4 dims/lane). No dummy slots except
// the final tail (R7's h4: rows avg deg 8 -> half of each 16-chunk dummied).

__global__ void spmm_bucket(const int* __restrict__ bstart, const uint2* __restrict__ edges,
                            const __half* __restrict__ Ein, __half* __restrict__ Eout,
                            int nrows) {
    __shared__ float acc[BROWS * ACC_STRIDE];   // 34.8 KB
    int blk = blockIdx.x;
    int t = threadIdx.x;
    for (int i = t; i < BROWS * ACC_STRIDE; i += 256) acc[i] = 0.0f;
    __syncthreads();

    int eb = bstart[blk];
    int ee = bstart[blk + 1];
    int wave = t >> 6, lane = t & 63;
    int g = lane >> 4, l = lane & 15;

    for (int k = eb + wave * 16; k < ee; k += 64) {
        uint2 ed[4];
#pragma unroll
        for (int j = 0; j < 4; j++) {
            int kk = k + 4 * j + g;
            ed[j] = (kk < ee) ? edges[kk] : make_uint2(0u, 0u);
        }
        ushort4 gv[4];
#pragma unroll
        for (int j = 0; j < 4; j++) {
            gv[j] = *(const ushort4*)(Ein + (size_t)(ed[j].x & 0x3FFFFu) * LATENT + 4 * l);
        }
#pragma unroll
        for (int j = 0; j < 4; j++) {
            float w = __uint_as_float(ed[j].y);        // 0.0 for tail dummies
            int rl = (int)(ed[j].x >> 18);
            const __half2* h2 = (const __half2*)&gv[j];
            float* dst = &acc[rl * ACC_STRIDE + 4 * l];
            atomicAdd(dst + 0, w * __low2float(h2[0]));
            atomicAdd(dst + 1, w * __high2float(h2[0]));
            atomicAdd(dst + 2, w * __low2float(h2[1]));
            atomicAdd(dst + 3, w * __high2float(h2[1]));
        }
    }
    __syncthreads();

    // coalesced fp16 writeout
    int rbase = blk * BROWS;
    int nr = nrows - rbase; if (nr > BROWS) nr = BROWS;
    __half2* out2 = (__half2*)(Eout + (size_t)rbase * LATENT);
    int total2 = nr * (LATENT / 2);
    for (int i = t; i < total2; i += 256) {
        int r = i >> 5, c2 = i & 31;
        out2[i] = __floats2half2_rn(acc[r * ACC_STRIDE + 2 * c2],
                                    acc[r * ACC_STRIDE + 2 * c2 + 1]);
    }
}

// ---------- epilogue: read E0 + all three layer tables directly ----------

__global__ void finalize2(const int* __restrict__ users, const int* __restrict__ pos,
                          const int* __restrict__ neg, const float* __restrict__ E0,
                          const __half* __restrict__ E1, const __half* __restrict__ E2,
                          const __half* __restrict__ E3, float* __restrict__ out, int batch) {
    int t = blockIdx.x * blockDim.x + threadIdx.x;
    int total = 3 * batch * LATENT;
    if (t >= total) return;
    int d = t & 63;
    int b = t >> 6;
    int g = b / batch;
    int bb = b - g * batch;
    int r = (g == 0) ? users[bb] : (g == 1) ? (N_USERS_C + pos[bb]) : (N_USERS_C + neg[bb]);
    size_t idx = (size_t)r * LATENT + d;
    float e0 = E0[idx];
    float s = e0 + __half2float(E1[idx]) + __half2float(E2[idx]) + __half2float(E3[idx]);
    out[t] = 0.25f * s;
    out[total + t] = e0;
}

extern "C" void kernel_launch(void* const* d_in, const int* in_sizes, int n_in,
                              void* d_out, int out_size, void* d_ws, size_t ws_size,
                              hipStream_t stream) {
    const int*   users = (const int*)d_in[0];
    const int*   pos   = (const int*)d_in[1];
    const int*   neg   = (const int*)d_in[2];
    const float* E0    = (const float*)d_in[3];
    const int*   row   = (const int*)d_in[4];
    const int*   col   = (const int*)d_in[5];
    const float* vals  = (const float*)d_in[6];
    float*       out   = (float*)d_out;

    const int batch  = in_sizes[0];          // 4096
    const int nnz    = in_sizes[4];          // 1,200,000
    const int ntotal = in_sizes[3] / LATENT; // 150,000
    const int nbuck  = (ntotal + BROWS - 1) / BROWS;   // 1172

    auto align256 = [](size_t x) { return (x + 255) & ~(size_t)255; };

    const size_t hbufBytes  = align256((size_t)ntotal * LATENT * sizeof(__half)); // 19.2 MB
    const size_t edgeBytes  = align256((size_t)nnz * sizeof(uint2));              // 9.6 MB
    const size_t bsBytes    = align256((size_t)(nbuck + 1) * sizeof(int));
    const size_t bcBytes    = align256((size_t)nbuck * sizeof(int));

    char* p = (char*)d_ws;
    __half* E0h   = (__half*)p;             p += hbufBytes;
    __half* bufA  = (__half*)p;             p += hbufBytes;   // E1
    __half* bufB  = (__half*)p;             p += hbufBytes;   // E2
    __half* bufC  = (__half*)p;             p += hbufBytes;   // E3
    uint2* edges  = (uint2*)p;              p += edgeBytes;
    int*   bstart = (int*)p;                p += bsBytes;
    int*   bcur   = (int*)p;                p += bcBytes;
    int*   bcnt   = (int*)p;                p += bcBytes;

    hipMemsetAsync(bcnt, 0, bcBytes, stream);

    const int threads = 256;
    const int sortBlocks = (nnz + SORT_CHUNK - 1) / SORT_CHUNK;   // 293
    const int gBlocks = (3 * batch * LATENT + threads - 1) / threads;
    const int n4 = ntotal * LATENT / 4;
    const int cBlocks = (n4 + threads - 1) / threads;

    // Build bucket-grouped edge list
    bhist_kernel<<<sortBlocks, SORT_T, 0, stream>>>(row, bcnt, nnz, nbuck);
    bscan_kernel<<<1, SORT_T, 0, stream>>>(bcnt, bstart, bcur, nbuck);
    sort_kernel<<<sortBlocks, SORT_T, 0, stream>>>(row, col, vals, bcur, edges, nnz, nbuck);

    // Convert E0 -> fp16 table
    conv_kernel<<<cBlocks, threads, 0, stream>>>(E0, E0h, n4);

    // Three SpMM layers into separate tables
    spmm_bucket<<<nbuck, threads, 0, stream>>>(bstart, edges, E0h, bufA, ntotal);
    spmm_bucket<<<nbuck, threads, 0, stream>>>(bstart, edges, bufA, bufB, ntotal);
    spmm_bucket<<<nbuck, threads, 0, stream>>>(bstart, edges, bufB, bufC, ntotal);

    finalize2<<<gBlocks, threads, 0, stream>>>(users, pos, neg, E0, bufA, bufB, bufC, out, batch);
}

// Round 10
// 293.393 us; speedup vs baseline: 5.1088x; 5.1088x over previous
//
#include <hip/hip_runtime.h>
#include <hip/hip_fp16.h>

#define LATENT 64
#define N_USERS_C 100000

#define BROWS 128
#define LOG_BROWS 7
#define NBUCK_MAX 1280         // >= ceil(150000/128) = 1172
#define NBLKA_MAX 512          // >= ceil(nnz/4096) = 293
#define SORT_T 256
#define SORT_E 16
#define SORT_CHUNK (SORT_T * SORT_E)   // 4096 edges per block
#define BUCK_CAP 4608          // max edges per 128-row bucket (mean ~1536, sd ~39)

// ---------- Phase A: per-block LDS bucket sort, fully-coalesced output ----------
// Payload: .x = col | (rowLocal<<18)  (col < 2^18, rowLocal < 128), .y = val bits.
// Block writes its 4096 bucket-grouped edges to aux[blk*4096..] (coalesced),
// plus cntmat[blk][b], srcmat[blk][b] and atomic bucket totals.

__global__ void sortA_kernel(const int* __restrict__ row, const int* __restrict__ col,
                             const float* __restrict__ vals,
                             uint2* __restrict__ aux, int* __restrict__ cntmat,
                             int* __restrict__ srcmat, int* __restrict__ bcnt,
                             int nnz, int nbuck) {
    __shared__ int cnt[NBUCK_MAX];
    __shared__ int off[NBUCK_MAX];
    __shared__ int part[SORT_T];
    __shared__ uint2 buf[SORT_CHUNK];   // 32 KB
    int t = threadIdx.x, blk = blockIdx.x;
    int base = blk * SORT_CHUNK;

    for (int i = t; i < nbuck; i += SORT_T) cnt[i] = 0;
    __syncthreads();

    int   eb[SORT_E];
    uint2 pl[SORT_E];
#pragma unroll
    for (int j = 0; j < SORT_E; j++) {
        int e = base + j * SORT_T + t;
        if (e < nnz) {
            int r = row[e];
            int b = r >> LOG_BROWS;
            eb[j] = b;
            pl[j] = make_uint2((unsigned)col[e] | ((unsigned)(r & (BROWS - 1)) << 18),
                               (unsigned)__float_as_int(vals[e]));
            atomicAdd(&cnt[b], 1);
        } else {
            eb[j] = -1;
        }
    }
    __syncthreads();

    // exclusive scan cnt -> off (parallel)
    int chunk = (nbuck + SORT_T - 1) / SORT_T;
    int lo = t * chunk, hi = lo + chunk; if (hi > nbuck) hi = nbuck;
    int s = 0;
    for (int i = lo; i < hi; i++) s += cnt[i];
    part[t] = s;
    __syncthreads();
    for (int o = 1; o < SORT_T; o <<= 1) {
        int x = (t >= o) ? part[t - o] : 0;
        __syncthreads();
        part[t] += x;
        __syncthreads();
    }
    int run = (t == 0) ? 0 : part[t - 1];
    for (int i = lo; i < hi; i++) { off[i] = run; run += cnt[i]; }
    __syncthreads();

    // place into LDS (bucket-grouped)
#pragma unroll
    for (int j = 0; j < SORT_E; j++) {
        if (eb[j] >= 0) {
            int p = atomicAdd(&off[eb[j]], 1);
            buf[p] = pl[j];
        }
    }
    __syncthreads();

    // per-(block,bucket) tables + global totals; off[b] is now end-of-bucket
    for (int b = t; b < nbuck; b += SORT_T) {
        int c = cnt[b];
        int beg = off[b] - c;
        cntmat[(size_t)blk * nbuck + b] = c;
        srcmat[(size_t)blk * nbuck + b] = beg;
        if (c) atomicAdd(&bcnt[b], c);
    }
    // coalesced chunk writeout
    int nvalid = nnz - base; if (nvalid > SORT_CHUNK) nvalid = SORT_CHUNK;
    for (int i = t; i < nvalid; i += SORT_T) aux[base + i] = buf[i];
}

// ---------- bucket-start exclusive scan (single block) ----------

__global__ void bscan_kernel(const int* __restrict__ bcnt, int* __restrict__ bstart,
                             int nbuck) {
    __shared__ int part[SORT_T];
    int t = threadIdx.x;
    int chunk = (nbuck + SORT_T - 1) / SORT_T;
    int lo = t * chunk, hi = lo + chunk; if (hi > nbuck) hi = nbuck;
    int s = 0;
    for (int i = lo; i < hi; i++) s += bcnt[i];
    part[t] = s;
    __syncthreads();
    for (int o = 1; o < SORT_T; o <<= 1) {
        int x = (t >= o) ? part[t - o] : 0;
        __syncthreads();
        part[t] += x;
        __syncthreads();
    }
    int run = (t == 0) ? 0 : part[t - 1];
    for (int i = lo; i < hi; i++) { bstart[i] = run; run += bcnt[i]; }
    if (t == SORT_T - 1) bstart[nbuck] = run;   // = nnz
}

// ---------- Phase B: one block per bucket -> exact CSR, coalesced writes ----------

__global__ void sortB_kernel(const uint2* __restrict__ aux, const int* __restrict__ cntmat,
                             const int* __restrict__ srcmat, const int* __restrict__ bstart,
                             int2* __restrict__ edges, int* __restrict__ startOut,
                             int nblkA, int nbuck, int ntotal, int nnz) {
    __shared__ int rc[NBLKA_MAX], rs[NBLKA_MAX], roff[NBLKA_MAX];
    __shared__ int part[SORT_T];
    __shared__ uint2 buf[BUCK_CAP];     // 36.9 KB
    __shared__ int cnt128[BROWS], off128[BROWS];
    int b = blockIdx.x, t = threadIdx.x;
    int base = bstart[b];
    int tot = bstart[b + 1] - base;

    for (int i = t; i < nblkA; i += SORT_T) {
        rc[i] = cntmat[(size_t)i * nbuck + b];
        rs[i] = srcmat[(size_t)i * nbuck + b];
    }
    if (t < BROWS) cnt128[t] = 0;
    __syncthreads();

    // exclusive scan of run counts (parallel)
    int chunk = (nblkA + SORT_T - 1) / SORT_T;
    int lo = t * chunk, hi = lo + chunk; if (hi > nblkA) hi = nblkA;
    int s = 0;
    for (int i = lo; i < hi; i++) s += rc[i];
    part[t] = s;
    __syncthreads();
    for (int o = 1; o < SORT_T; o <<= 1) {
        int x = (t >= o) ? part[t - o] : 0;
        __syncthreads();
        part[t] += x;
        __syncthreads();
    }
    int run = (t == 0) ? 0 : part[t - 1];
    for (int i = lo; i < hi; i++) { roff[i] = run; run += rc[i]; }
    __syncthreads();

    // gather this bucket's runs into LDS
    for (int i = t; i < nblkA; i += SORT_T) {
        int c = rc[i], sOff = rs[i], o = roff[i];
        const uint2* src = aux + (size_t)i * SORT_CHUNK + sOff;
        for (int j = 0; j < c; j++) buf[o + j] = src[j];
    }
    __syncthreads();

    // count rows
    for (int i = t; i < tot; i += SORT_T) atomicAdd(&cnt128[buf[i].x >> 18], 1);
    __syncthreads();

    // exclusive scan of 128 row counts (parallel via part[])
    part[t] = (t < BROWS) ? cnt128[t] : 0;
    __syncthreads();
    for (int o = 1; o < SORT_T; o <<= 1) {
        int x = (t >= o) ? part[t - o] : 0;
        __syncthreads();
        part[t] += x;
        __syncthreads();
    }
    if (t < BROWS) off128[t] = (t == 0) ? 0 : part[t - 1];
    __syncthreads();

    // emit start[] for this bucket's rows (before off128 is mutated)
    int rbase = b * BROWS;
    int nr = ntotal - rbase; if (nr > BROWS) nr = BROWS;
    if (t < nr) startOut[rbase + t] = base + off128[t];
    if (b == nbuck - 1 && t == 0) startOut[ntotal] = nnz;
    __syncthreads();

    // place edges in CSR order (destination region is a contiguous ~8KB window)
    for (int i = t; i < tot; i += SORT_T) {
        uint2 e = buf[i];
        int p = atomicAdd(&off128[e.x >> 18], 1);
        edges[base + p] = make_int2((int)(e.x & 0x3FFFFu), (int)e.y);
    }
}

// fp32 -> fp16 table conversion, 4 elements/thread.
__global__ void conv_kernel(const float* __restrict__ in, __half* __restrict__ outh, int n4) {
    int i = blockIdx.x * blockDim.x + threadIdx.x;
    if (i >= n4) return;
    float4 v = ((const float4*)in)[i];
    __half2* o = (__half2*)outh;
    o[2 * i]     = __floats2half2_rn(v.x, v.y);
    o[2 * i + 1] = __floats2half2_rn(v.z, v.w);
}

// ---------- Row-parallel SpMM (R7, known-good): 4 edges per vmem instruction ----------

__global__ void spmm_csr_h4(const int* __restrict__ start,
                            const int2* __restrict__ edges,
                            const __half* __restrict__ Ein, __half* __restrict__ Eout,
                            int nrows) {
    int t = blockIdx.x * blockDim.x + threadIdx.x;
    int r = t >> 6;
    if (r >= nrows) return;
    int lane = t & 63;
    int g = lane >> 4;           // edge group 0..3
    int l = lane & 15;           // dims 4l..4l+3
    int b = start[r];
    int e = start[r + 1];
    float a0 = 0.f, a1 = 0.f, a2 = 0.f, a3 = 0.f;
    for (int k = b; k < e; k += 16) {
        int2 ed[4];
#pragma unroll
        for (int j = 0; j < 4; j++) {
            int kk = k + 4 * j + g;
            ed[j] = (kk < e) ? edges[kk] : make_int2(0, 0);   // 4 edges / instr
        }
        ushort4 gv[4];
#pragma unroll
        for (int j = 0; j < 4; j++) {
            gv[j] = *(const ushort4*)(Ein + (size_t)ed[j].x * LATENT + 4 * l);
        }
#pragma unroll
        for (int j = 0; j < 4; j++) {
            float w = __int_as_float(ed[j].y);                // 0.0 for tail dummies
            const __half2* h2 = (const __half2*)&gv[j];
            a0 += w * __low2float(h2[0]);
            a1 += w * __high2float(h2[0]);
            a2 += w * __low2float(h2[1]);
            a3 += w * __high2float(h2[1]);
        }
    }
    a0 += __shfl_xor(a0, 16, 64); a0 += __shfl_xor(a0, 32, 64);
    a1 += __shfl_xor(a1, 16, 64); a1 += __shfl_xor(a1, 32, 64);
    a2 += __shfl_xor(a2, 16, 64); a2 += __shfl_xor(a2, 32, 64);
    a3 += __shfl_xor(a3, 16, 64); a3 += __shfl_xor(a3, 32, 64);
    if (g == 0) {
        union { ushort4 u; __half2 h[2]; } o;
        o.h[0] = __floats2half2_rn(a0, a1);
        o.h[1] = __floats2half2_rn(a2, a3);
        *(ushort4*)(Eout + (size_t)r * LATENT + 4 * l) = o.u;
    }
}

// ---------- epilogue ----------

__global__ void finalize2(const int* __restrict__ users, const int* __restrict__ pos,
                          const int* __restrict__ neg, const float* __restrict__ E0,
                          const __half* __restrict__ E1, const __half* __restrict__ E2,
                          const __half* __restrict__ E3, float* __restrict__ out, int batch) {
    int t = blockIdx.x * blockDim.x + threadIdx.x;
    int total = 3 * batch * LATENT;
    if (t >= total) return;
    int d = t & 63;
    int b = t >> 6;
    int g = b / batch;
    int bb = b - g * batch;
    int r = (g == 0) ? users[bb] : (g == 1) ? (N_USERS_C + pos[bb]) : (N_USERS_C + neg[bb]);
    size_t idx = (size_t)r * LATENT + d;
    float e0 = E0[idx];
    float s = e0 + __half2float(E1[idx]) + __half2float(E2[idx]) + __half2float(E3[idx]);
    out[t] = 0.25f * s;
    out[total + t] = e0;
}

extern "C" void kernel_launch(void* const* d_in, const int* in_sizes, int n_in,
                              void* d_out, int out_size, void* d_ws, size_t ws_size,
                              hipStream_t stream) {
    const int*   users = (const int*)d_in[0];
    const int*   pos   = (const int*)d_in[1];
    const int*   neg   = (const int*)d_in[2];
    const float* E0    = (const float*)d_in[3];
    const int*   row   = (const int*)d_in[4];
    const int*   col   = (const int*)d_in[5];
    const float* vals  = (const float*)d_in[6];
    float*       out   = (float*)d_out;

    const int batch  = in_sizes[0];          // 4096
    const int nnz    = in_sizes[4];          // 1,200,000
    const int ntotal = in_sizes[3] / LATENT; // 150,000
    const int nbuck  = (ntotal + BROWS - 1) / BROWS;       // 1172
    const int nblkA  = (nnz + SORT_CHUNK - 1) / SORT_CHUNK; // 293

    auto align256 = [](size_t x) { return (x + 255) & ~(size_t)255; };

    const size_t hbufBytes = align256((size_t)ntotal * LATENT * sizeof(__half)); // 19.2 MB
    const size_t edgeBytes = align256((size_t)nnz * sizeof(int2));               // 9.6 MB
    const size_t matBytes  = align256((size_t)nblkA * nbuck * sizeof(int));      // 1.38 MB
    const size_t stBytes   = align256((size_t)(ntotal + 1) * sizeof(int));
    const size_t bsBytes   = align256((size_t)(nbuck + 1) * sizeof(int));

    char* p = (char*)d_ws;
    __half* E0h     = (__half*)p;           p += hbufBytes;
    __half* bufA    = (__half*)p;           p += hbufBytes;   // E1
    __half* bufB    = (__half*)p;           p += hbufBytes;   // E2  (cntmat/srcmat alias: build-only)
    __half* bufC    = (__half*)p;           p += hbufBytes;   // E3  (aux alias: build-only)
    int2*   edges   = (int2*)p;             p += edgeBytes;   // final CSR edges
    int*    startA  = (int*)p;              p += stBytes;
    int*    bstart  = (int*)p;              p += bsBytes;
    int*    bcnt    = (int*)p;              p += bsBytes;
    // aliases (consumed before their host buffers are first written):
    uint2* aux    = (uint2*)bufC;                 // 9.6 MB < 19.2 MB; bufC written at layer 3
    int*   cntmat = (int*)bufB;                   // bufB written at layer 2
    int*   srcmat = (int*)((char*)bufB + matBytes);

    hipMemsetAsync(bcnt, 0, (size_t)nbuck * sizeof(int), stream);

    const int threads = 256;
    const int sBlocks = (ntotal * LATENT + threads - 1) / threads;
    const int gBlocks = (3 * batch * LATENT + threads - 1) / threads;
    const int n4 = ntotal * LATENT / 4;
    const int cBlocks = (n4 + threads - 1) / threads;

    // Build CSR: two-phase coalesced sort
    sortA_kernel<<<nblkA, SORT_T, 0, stream>>>(row, col, vals, aux, cntmat, srcmat,
                                               bcnt, nnz, nbuck);
    bscan_kernel<<<1, SORT_T, 0, stream>>>(bcnt, bstart, nbuck);
    conv_kernel<<<cBlocks, threads, 0, stream>>>(E0, E0h, n4);   // independent; fills gap
    sortB_kernel<<<nbuck, SORT_T, 0, stream>>>(aux, cntmat, srcmat, bstart,
                                               edges, startA, nblkA, nbuck, ntotal, nnz);

    // Three SpMM layers
    spmm_csr_h4<<<sBlocks, threads, 0, stream>>>(startA, edges, E0h, bufA, ntotal);
    spmm_csr_h4<<<sBlocks, threads, 0, stream>>>(startA, edges, bufA, bufB, ntotal);
    spmm_csr_h4<<<sBlocks, threads, 0, stream>>>(startA, edges, bufB, bufC, ntotal);

    finalize2<<<gBlocks, threads, 0, stream>>>(users, pos, neg, E0, bufA, bufB, bufC, out, batch);
}

// Round 11
// 269.262 us; speedup vs baseline: 5.5666x; 1.0896x over previous
//
#include <hip/hip_runtime.h>
#include <hip/hip_fp16.h>

#define LATENT 64
#define N_USERS_C 100000

#define BROWS 128
#define LOG_BROWS 7
#define NBUCK_MAX 1280         // >= ceil(150000/128) = 1172
#define NBLKA_MAX 512          // >= ceil(nnz/4096) = 293
#define SORT_T 256
#define SORT_E 16
#define SORT_CHUNK (SORT_T * SORT_E)   // 4096 edges per block
#define BUCK_CAP 4608          // max edges per 128-row bucket (mean ~1536)

// ---------- Phase A: per-block LDS bucket sort, fully-coalesced output ----------
// Payload: .x = col | (rowLocal<<18), .y = val bits.

__global__ void sortA_kernel(const int* __restrict__ row, const int* __restrict__ col,
                             const float* __restrict__ vals,
                             uint2* __restrict__ aux, int* __restrict__ cntmat,
                             int* __restrict__ srcmat, int* __restrict__ bcnt,
                             int nnz, int nbuck) {
    __shared__ int cnt[NBUCK_MAX];
    __shared__ int off[NBUCK_MAX];
    __shared__ int part[SORT_T];
    __shared__ uint2 buf[SORT_CHUNK];   // 32 KB
    int t = threadIdx.x, blk = blockIdx.x;
    int base = blk * SORT_CHUNK;

    for (int i = t; i < nbuck; i += SORT_T) cnt[i] = 0;
    __syncthreads();

    int   eb[SORT_E];
    uint2 pl[SORT_E];
#pragma unroll
    for (int j = 0; j < SORT_E; j++) {
        int e = base + j * SORT_T + t;
        if (e < nnz) {
            int r = row[e];
            int b = r >> LOG_BROWS;
            eb[j] = b;
            pl[j] = make_uint2((unsigned)col[e] | ((unsigned)(r & (BROWS - 1)) << 18),
                               (unsigned)__float_as_int(vals[e]));
            atomicAdd(&cnt[b], 1);
        } else {
            eb[j] = -1;
        }
    }
    __syncthreads();

    int chunk = (nbuck + SORT_T - 1) / SORT_T;
    int lo = t * chunk, hi = lo + chunk; if (hi > nbuck) hi = nbuck;
    int s = 0;
    for (int i = lo; i < hi; i++) s += cnt[i];
    part[t] = s;
    __syncthreads();
    for (int o = 1; o < SORT_T; o <<= 1) {
        int x = (t >= o) ? part[t - o] : 0;
        __syncthreads();
        part[t] += x;
        __syncthreads();
    }
    int run = (t == 0) ? 0 : part[t - 1];
    for (int i = lo; i < hi; i++) { off[i] = run; run += cnt[i]; }
    __syncthreads();

#pragma unroll
    for (int j = 0; j < SORT_E; j++) {
        if (eb[j] >= 0) {
            int p = atomicAdd(&off[eb[j]], 1);
            buf[p] = pl[j];
        }
    }
    __syncthreads();

    for (int b = t; b < nbuck; b += SORT_T) {
        int c = cnt[b];
        int beg = off[b] - c;
        cntmat[(size_t)blk * nbuck + b] = c;
        srcmat[(size_t)blk * nbuck + b] = beg;
        if (c) atomicAdd(&bcnt[b], c);
    }
    int nvalid = nnz - base; if (nvalid > SORT_CHUNK) nvalid = SORT_CHUNK;
    for (int i = t; i < nvalid; i += SORT_T) aux[base + i] = buf[i];
}

// ---------- bucket-start exclusive scan (single block) ----------

__global__ void bscan_kernel(const int* __restrict__ bcnt, int* __restrict__ bstart,
                             int nbuck) {
    __shared__ int part[SORT_T];
    int t = threadIdx.x;
    int chunk = (nbuck + SORT_T - 1) / SORT_T;
    int lo = t * chunk, hi = lo + chunk; if (hi > nbuck) hi = nbuck;
    int s = 0;
    for (int i = lo; i < hi; i++) s += bcnt[i];
    part[t] = s;
    __syncthreads();
    for (int o = 1; o < SORT_T; o <<= 1) {
        int x = (t >= o) ? part[t - o] : 0;
        __syncthreads();
        part[t] += x;
        __syncthreads();
    }
    int run = (t == 0) ? 0 : part[t - 1];
    for (int i = lo; i < hi; i++) { bstart[i] = run; run += bcnt[i]; }
    if (t == SORT_T - 1) bstart[nbuck] = run;   // = nnz
}

// ---------- Phase B: bucket -> CSR in DEGREE-SORTED slot order ----------
// Rows within a bucket are counting-sorted by degree (ascending); slot s
// of the bucket gets row rowOf[s]. start[]/edges[] are emitted in slot
// order; origRow[] maps slot -> original row. Consecutive slots then have
// near-equal degree, so spmm_slot's 4-rows-per-wave loop has ~no dummy
// iterations (R9's fixed 16-slot chunk burned ~50% of slots on dummies).

__global__ void sortB_kernel(const uint2* __restrict__ aux, const int* __restrict__ cntmat,
                             const int* __restrict__ srcmat, const int* __restrict__ bstart,
                             int2* __restrict__ edges, int* __restrict__ startOut,
                             int* __restrict__ origRow,
                             int nblkA, int nbuck, int ntotal, int nnz) {
    __shared__ int rc[NBLKA_MAX], rs[NBLKA_MAX], roff[NBLKA_MAX];
    __shared__ int part[SORT_T];
    __shared__ uint2 buf[BUCK_CAP];     // 36.9 KB
    __shared__ int cnt128[BROWS];       // per original row
    __shared__ int slotOf[BROWS];       // orig row -> sorted slot
    __shared__ int rowOf[BROWS];        // sorted slot -> orig row
    __shared__ int offS[BROWS];         // sorted-slot exclusive edge offset
    __shared__ int placeOff[BROWS];     // per orig row: mutable cursor
    __shared__ int dhist[64];
    int b = blockIdx.x, t = threadIdx.x;
    int base = bstart[b];
    int tot = bstart[b + 1] - base;
    int rbase = b * BROWS;
    int nr = ntotal - rbase; if (nr > BROWS) nr = BROWS;

    for (int i = t; i < nblkA; i += SORT_T) {
        rc[i] = cntmat[(size_t)i * nbuck + b];
        rs[i] = srcmat[(size_t)i * nbuck + b];
    }
    if (t < BROWS) cnt128[t] = 0;
    if (t < 64) dhist[t] = 0;
    __syncthreads();

    // scan run counts
    int chunk = (nblkA + SORT_T - 1) / SORT_T;
    int lo = t * chunk, hi = lo + chunk; if (hi > nblkA) hi = nblkA;
    int s = 0;
    for (int i = lo; i < hi; i++) s += rc[i];
    part[t] = s;
    __syncthreads();
    for (int o = 1; o < SORT_T; o <<= 1) {
        int x = (t >= o) ? part[t - o] : 0;
        __syncthreads();
        part[t] += x;
        __syncthreads();
    }
    int run = (t == 0) ? 0 : part[t - 1];
    for (int i = lo; i < hi; i++) { roff[i] = run; run += rc[i]; }
    __syncthreads();

    // gather this bucket's runs into LDS
    for (int i = t; i < nblkA; i += SORT_T) {
        int c = rc[i], sOff = rs[i], o = roff[i];
        const uint2* src = aux + (size_t)i * SORT_CHUNK + sOff;
        for (int j = 0; j < c; j++) buf[o + j] = src[j];
    }
    __syncthreads();

    // per-row counts
    for (int i = t; i < tot; i += SORT_T) atomicAdd(&cnt128[buf[i].x >> 18], 1);
    __syncthreads();

    // degree histogram (ascending counting sort of rows by degree)
    if (t < nr) { int d = min(cnt128[t], 63); atomicAdd(&dhist[d], 1); }
    __syncthreads();
    part[t] = (t < 64) ? dhist[t] : 0;
    __syncthreads();
    for (int o = 1; o < 64; o <<= 1) {
        int x = (t >= o) ? part[t - o] : 0;
        __syncthreads();
        part[t] += x;
        __syncthreads();
    }
    if (t < 64) dhist[t] = (t == 0) ? 0 : part[t - 1];   // reuse as running offset
    __syncthreads();
    if (t < nr) {
        int d = min(cnt128[t], 63);
        int sl = atomicAdd(&dhist[d], 1);
        slotOf[t] = sl;
        rowOf[sl] = t;
    }
    __syncthreads();

    // sorted-slot count scan
    part[t] = (t < nr) ? cnt128[rowOf[t]] : 0;
    __syncthreads();
    for (int o = 1; o < SORT_T; o <<= 1) {
        int x = (t >= o) ? part[t - o] : 0;
        __syncthreads();
        part[t] += x;
        __syncthreads();
    }
    if (t < nr) offS[t] = (t == 0) ? 0 : part[t - 1];
    __syncthreads();

    // emit start[], origRow[], and per-orig-row place cursors
    if (t < nr) {
        startOut[rbase + t] = base + offS[t];
        origRow[rbase + t]  = rbase + rowOf[t];
        placeOff[t] = offS[slotOf[t]];
    }
    if (b == nbuck - 1 && t == 0) startOut[ntotal] = nnz;
    __syncthreads();

    // place edges (destination: contiguous ~12KB bucket window)
    for (int i = t; i < tot; i += SORT_T) {
        uint2 e = buf[i];
        int rl = (int)(e.x >> 18);
        int p = atomicAdd(&placeOff[rl], 1);
        edges[base + p] = make_int2((int)(e.x & 0x3FFFFu), (int)e.y);
    }
}

// fp32 -> fp16 table conversion, 4 elements/thread.
__global__ void conv_kernel(const float* __restrict__ in, __half* __restrict__ outh, int n4) {
    int i = blockIdx.x * blockDim.x + threadIdx.x;
    if (i >= n4) return;
    float4 v = ((const float4*)in)[i];
    __half2* o = (__half2*)outh;
    o[2 * i]     = __floats2half2_rn(v.x, v.y);
    o[2 * i + 1] = __floats2half2_rn(v.z, v.w);
}

// ---------- SpMM over degree-sorted slots ----------
// Wave = 4 slots (rows); lane-group g (16 lanes, 4 dims/lane) owns slot
// 4w+g entirely: 4 edges/iter, no cross-group reduction, full-width store.
// Neighbor slots have ~equal degree (sortB), so group loop bounds match and
// dummy slots only appear in the last iteration's tail.

__global__ void spmm_slot(const int* __restrict__ start, const int* __restrict__ origRow,
                          const int2* __restrict__ edges,
                          const __half* __restrict__ Ein, __half* __restrict__ Eout,
                          int nslots) {
    int t = blockIdx.x * blockDim.x + threadIdx.x;
    int w = t >> 6;
    int lane = t & 63;
    int g = lane >> 4, l = lane & 15;
    int s = 4 * w + g;
    if (s >= nslots) return;
    int b = start[s];
    int e = start[s + 1];
    int ro = origRow[s];
    float a0 = 0.f, a1 = 0.f, a2 = 0.f, a3 = 0.f;
    for (int k = b; k < e; k += 4) {
        int2 ed[4];
#pragma unroll
        for (int j = 0; j < 4; j++) {
            int kk = k + j;
            ed[j] = (kk < e) ? edges[kk] : make_int2(0, 0);
        }
        ushort4 gv[4];
#pragma unroll
        for (int j = 0; j < 4; j++) {
            gv[j] = *(const ushort4*)(Ein + (size_t)ed[j].x * LATENT + 4 * l);
        }
#pragma unroll
        for (int j = 0; j < 4; j++) {
            float wv = __int_as_float(ed[j].y);   // 0.0 for tail dummies
            const __half2* h2 = (const __half2*)&gv[j];
            a0 += wv * __low2float(h2[0]);
            a1 += wv * __high2float(h2[0]);
            a2 += wv * __low2float(h2[1]);
            a3 += wv * __high2float(h2[1]);
        }
    }
    union { ushort4 u; __half2 h[2]; } o;
    o.h[0] = __floats2half2_rn(a0, a1);
    o.h[1] = __floats2half2_rn(a2, a3);
    *(ushort4*)(Eout + (size_t)ro * LATENT + 4 * l) = o.u;   // all 64 lanes store
}

// ---------- epilogue ----------

__global__ void finalize2(const int* __restrict__ users, const int* __restrict__ pos,
                          const int* __restrict__ neg, const float* __restrict__ E0,
                          const __half* __restrict__ E1, const __half* __restrict__ E2,
                          const __half* __restrict__ E3, float* __restrict__ out, int batch) {
    int t = blockIdx.x * blockDim.x + threadIdx.x;
    int total = 3 * batch * LATENT;
    if (t >= total) return;
    int d = t & 63;
    int b = t >> 6;
    int g = b / batch;
    int bb = b - g * batch;
    int r = (g == 0) ? users[bb] : (g == 1) ? (N_USERS_C + pos[bb]) : (N_USERS_C + neg[bb]);
    size_t idx = (size_t)r * LATENT + d;
    float e0 = E0[idx];
    float s = e0 + __half2float(E1[idx]) + __half2float(E2[idx]) + __half2float(E3[idx]);
    out[t] = 0.25f * s;
    out[total + t] = e0;
}

extern "C" void kernel_launch(void* const* d_in, const int* in_sizes, int n_in,
                              void* d_out, int out_size, void* d_ws, size_t ws_size,
                              hipStream_t stream) {
    const int*   users = (const int*)d_in[0];
    const int*   pos   = (const int*)d_in[1];
    const int*   neg   = (const int*)d_in[2];
    const float* E0    = (const float*)d_in[3];
    const int*   row   = (const int*)d_in[4];
    const int*   col   = (const int*)d_in[5];
    const float* vals  = (const float*)d_in[6];
    float*       out   = (float*)d_out;

    const int batch  = in_sizes[0];          // 4096
    const int nnz    = in_sizes[4];          // 1,200,000
    const int ntotal = in_sizes[3] / LATENT; // 150,000
    const int nbuck  = (ntotal + BROWS - 1) / BROWS;        // 1172
    const int nblkA  = (nnz + SORT_CHUNK - 1) / SORT_CHUNK; // 293

    auto align256 = [](size_t x) { return (x + 255) & ~(size_t)255; };

    const size_t hbufBytes = align256((size_t)ntotal * LATENT * sizeof(__half)); // 19.2 MB
    const size_t edgeBytes = align256((size_t)nnz * sizeof(int2));               // 9.6 MB
    const size_t matBytes  = align256((size_t)nblkA * nbuck * sizeof(int));      // 1.38 MB
    const size_t stBytes   = align256((size_t)(ntotal + 1) * sizeof(int));
    const size_t bsBytes   = align256((size_t)(nbuck + 1) * sizeof(int));

    char* p = (char*)d_ws;
    __half* E0h     = (__half*)p;           p += hbufBytes;
    __half* bufA    = (__half*)p;           p += hbufBytes;   // E1
    __half* bufB    = (__half*)p;           p += hbufBytes;   // E2 (cntmat/srcmat alias: build-only)
    __half* bufC    = (__half*)p;           p += hbufBytes;   // E3 (aux alias: build-only)
    int2*   edges   = (int2*)p;             p += edgeBytes;   // CSR edges, slot order
    int*    startA  = (int*)p;              p += stBytes;     // per-slot edge offsets
    int*    origRow = (int*)p;              p += stBytes;     // slot -> original row
    int*    bstart  = (int*)p;              p += bsBytes;
    int*    bcnt    = (int*)p;              p += bsBytes;
    // aliases (consumed before their host buffers are first written):
    uint2* aux    = (uint2*)bufC;                 // bufC written at layer 3
    int*   cntmat = (int*)bufB;                   // bufB written at layer 2
    int*   srcmat = (int*)((char*)bufB + matBytes);

    hipMemsetAsync(bcnt, 0, (size_t)nbuck * sizeof(int), stream);

    const int threads = 256;
    const int slotWaves = (ntotal + 3) / 4;                       // 37500
    const int spBlocks = (slotWaves * 64 + threads - 1) / threads; // 9375
    const int gBlocks = (3 * batch * LATENT + threads - 1) / threads;
    const int n4 = ntotal * LATENT / 4;
    const int cBlocks = (n4 + threads - 1) / threads;

    // Build degree-sorted CSR: two-phase coalesced sort
    sortA_kernel<<<nblkA, SORT_T, 0, stream>>>(row, col, vals, aux, cntmat, srcmat,
                                               bcnt, nnz, nbuck);
    bscan_kernel<<<1, SORT_T, 0, stream>>>(bcnt, bstart, nbuck);
    conv_kernel<<<cBlocks, threads, 0, stream>>>(E0, E0h, n4);   // independent; fills gap
    sortB_kernel<<<nbuck, SORT_T, 0, stream>>>(aux, cntmat, srcmat, bstart,
                                               edges, startA, origRow,
                                               nblkA, nbuck, ntotal, nnz);

    // Three SpMM layers
    spmm_slot<<<spBlocks, threads, 0, stream>>>(startA, origRow, edges, E0h, bufA, ntotal);
    spmm_slot<<<spBlocks, threads, 0, stream>>>(startA, origRow, edges, bufA, bufB, ntotal);
    spmm_slot<<<spBlocks, threads, 0, stream>>>(startA, origRow, edges, bufB, bufC, ntotal);

    finalize2<<<gBlocks, threads, 0, stream>>>(users, pos, neg, E0, bufA, bufB, bufC, out, batch);
}

// Round 12
// 232.734 us; speedup vs baseline: 6.4403x; 1.1569x over previous
//
#include <hip/hip_runtime.h>
#include <hip/hip_fp16.h>

#define LATENT 64
#define N_USERS_C 100000

#define BROWS 128
#define LOG_BROWS 7
#define NBUCK_MAX 1280         // >= ceil(150000/128) = 1172
#define NBLKA_MAX 512          // >= ceil(nnz/4096) = 293
#define SORT_T 256
#define SORT_E 16
#define SORT_CHUNK (SORT_T * SORT_E)   // 4096 edges per block
#define BUCK_CAP 4608          // max edges per 128-row bucket (item-bucket mean ~1536)

// Edge payload: col:18 | val-e4m10:14  (exp bias 0x77 -> covers 2^-8..2^7;
// vals in [0.022, 1.0] -> exp4 in [2,8]; enc==0 reserved for "zero weight").
__device__ __forceinline__ unsigned enc_val14(float v) {
    unsigned vb = (unsigned)__float_as_int(v) + 0x1000u;            // round to nearest
    return (((vb >> 23) - 0x77u) << 10) | ((vb >> 13) & 0x3FFu);    // 14 bits
}
__device__ __forceinline__ float dec_val14(unsigned m) {
    return __uint_as_float(m ? ((((m >> 10) + 0x77u) << 23) | ((m & 0x3FFu) << 13)) : 0u);
}

// ---------- Phase A: per-block LDS bucket sort, fully-coalesced output ----------
// aux[i] = col | enc14<<18 (4B); rowloc[i] = row & 127 (1B).

__global__ void sortA_kernel(const int* __restrict__ row, const int* __restrict__ col,
                             const float* __restrict__ vals,
                             unsigned* __restrict__ aux, unsigned char* __restrict__ rowloc,
                             int* __restrict__ cntmat, int* __restrict__ srcmat,
                             int* __restrict__ bcnt, int nnz, int nbuck) {
    __shared__ int cnt[NBUCK_MAX];
    __shared__ int off[NBUCK_MAX];
    __shared__ int part[SORT_T];
    __shared__ unsigned buf[SORT_CHUNK];        // 16 KB
    __shared__ unsigned char rbuf[SORT_CHUNK];  // 4 KB
    int t = threadIdx.x, blk = blockIdx.x;
    int base = blk * SORT_CHUNK;

    for (int i = t; i < nbuck; i += SORT_T) cnt[i] = 0;
    __syncthreads();

    int      eb[SORT_E];
    unsigned pl[SORT_E];
    unsigned char rl8[SORT_E];
#pragma unroll
    for (int j = 0; j < SORT_E; j++) {
        int e = base + j * SORT_T + t;
        if (e < nnz) {
            int r = row[e];
            int b = r >> LOG_BROWS;
            eb[j] = b;
            pl[j] = (unsigned)col[e] | (enc_val14(vals[e]) << 18);
            rl8[j] = (unsigned char)(r & (BROWS - 1));
            atomicAdd(&cnt[b], 1);
        } else {
            eb[j] = -1;
        }
    }
    __syncthreads();

    int chunk = (nbuck + SORT_T - 1) / SORT_T;
    int lo = t * chunk, hi = lo + chunk; if (hi > nbuck) hi = nbuck;
    int s = 0;
    for (int i = lo; i < hi; i++) s += cnt[i];
    part[t] = s;
    __syncthreads();
    for (int o = 1; o < SORT_T; o <<= 1) {
        int x = (t >= o) ? part[t - o] : 0;
        __syncthreads();
        part[t] += x;
        __syncthreads();
    }
    int run = (t == 0) ? 0 : part[t - 1];
    for (int i = lo; i < hi; i++) { off[i] = run; run += cnt[i]; }
    __syncthreads();

#pragma unroll
    for (int j = 0; j < SORT_E; j++) {
        if (eb[j] >= 0) {
            int p = atomicAdd(&off[eb[j]], 1);
            buf[p] = pl[j];
            rbuf[p] = rl8[j];
        }
    }
    __syncthreads();

    for (int b = t; b < nbuck; b += SORT_T) {
        int c = cnt[b];
        int beg = off[b] - c;
        cntmat[(size_t)blk * nbuck + b] = c;
        srcmat[(size_t)blk * nbuck + b] = beg;
        if (c) atomicAdd(&bcnt[b], c);
    }
    int nvalid = nnz - base; if (nvalid > SORT_CHUNK) nvalid = SORT_CHUNK;
    for (int i = t; i < nvalid; i += SORT_T) {
        aux[base + i] = buf[i];
        rowloc[base + i] = rbuf[i];
    }
}

// ---------- bucket-start exclusive scan (single block) ----------

__global__ void bscan_kernel(const int* __restrict__ bcnt, int* __restrict__ bstart,
                             int nbuck) {
    __shared__ int part[SORT_T];
    int t = threadIdx.x;
    int chunk = (nbuck + SORT_T - 1) / SORT_T;
    int lo = t * chunk, hi = lo + chunk; if (hi > nbuck) hi = nbuck;
    int s = 0;
    for (int i = lo; i < hi; i++) s += bcnt[i];
    part[t] = s;
    __syncthreads();
    for (int o = 1; o < SORT_T; o <<= 1) {
        int x = (t >= o) ? part[t - o] : 0;
        __syncthreads();
        part[t] += x;
        __syncthreads();
    }
    int run = (t == 0) ? 0 : part[t - 1];
    for (int i = lo; i < hi; i++) { bstart[i] = run; run += bcnt[i]; }
    if (t == SORT_T - 1) bstart[nbuck] = run;   // = nnz
}

// ---------- Phase B: bucket -> degree-sorted-slot CSR, coalesced gather ----------
// Gather uses per-edge binary search over run offsets (consecutive threads hit
// consecutive aux addresses within a run) instead of R10's per-thread serial
// run-copy loops. Rows counting-sorted by degree; edges emitted as 4B packed.

__global__ void sortB_kernel(const unsigned* __restrict__ aux,
                             const unsigned char* __restrict__ rowloc,
                             const int* __restrict__ cntmat, const int* __restrict__ srcmat,
                             const int* __restrict__ bstart,
                             unsigned* __restrict__ edges, int* __restrict__ startOut,
                             int* __restrict__ origRow,
                             int nblkA, int nbuck, int ntotal, int nnz) {
    __shared__ int rs[NBLKA_MAX], roff[NBLKA_MAX + 1];
    __shared__ int part[SORT_T];
    __shared__ unsigned buf[BUCK_CAP];          // 18.4 KB
    __shared__ unsigned char rbuf[BUCK_CAP];    // 4.6 KB
    __shared__ int cnt128[BROWS];
    __shared__ int slotOf[BROWS];
    __shared__ int rowOf[BROWS];
    __shared__ int offS[BROWS];
    __shared__ int placeOff[BROWS];
    __shared__ int dhist[64];
    int b = blockIdx.x, t = threadIdx.x;
    int base = bstart[b];
    int tot = bstart[b + 1] - base;
    int rbase = b * BROWS;
    int nr = ntotal - rbase; if (nr > BROWS) nr = BROWS;

    // run counts -> exclusive offsets (with sentinel)
    int chunk = (nblkA + SORT_T - 1) / SORT_T;
    int lo = t * chunk, hi = lo + chunk; if (hi > nblkA) hi = nblkA;
    int rcl[8];   // chunk <= ceil(293/256)=2, but keep margin
    int s = 0;
    for (int i = lo; i < hi; i++) {
        int c = cntmat[(size_t)i * nbuck + b];
        rcl[i - lo] = c;
        rs[i] = srcmat[(size_t)i * nbuck + b];
        s += c;
    }
    part[t] = s;
    if (t < BROWS) cnt128[t] = 0;
    if (t < 64) dhist[t] = 0;
    __syncthreads();
    for (int o = 1; o < SORT_T; o <<= 1) {
        int x = (t >= o) ? part[t - o] : 0;
        __syncthreads();
        part[t] += x;
        __syncthreads();
    }
    int run = (t == 0) ? 0 : part[t - 1];
    for (int i = lo; i < hi; i++) { roff[i] = run; run += rcl[i - lo]; }
    if (t == SORT_T - 1) roff[nblkA] = part[SORT_T - 1];   // sentinel = tot
    __syncthreads();

    // coalesced gather: edge i -> binary search run r (largest with roff[r] <= i)
    for (int i = t; i < tot; i += SORT_T) {
        int lo2 = 0, hi2 = nblkA;
        while (hi2 - lo2 > 1) {
            int mid = (lo2 + hi2) >> 1;
            if (roff[mid] <= i) lo2 = mid; else hi2 = mid;
        }
        size_t src = (size_t)lo2 * SORT_CHUNK + rs[lo2] + (i - roff[lo2]);
        buf[i] = aux[src];
        unsigned char rl = rowloc[src];
        rbuf[i] = rl;
        atomicAdd(&cnt128[rl], 1);
    }
    __syncthreads();

    // degree histogram -> ascending counting sort of rows by degree
    if (t < nr) { int d = min(cnt128[t], 63); atomicAdd(&dhist[d], 1); }
    __syncthreads();
    part[t] = (t < 64) ? dhist[t] : 0;
    __syncthreads();
    for (int o = 1; o < 64; o <<= 1) {
        int x = (t >= o) ? part[t - o] : 0;
        __syncthreads();
        part[t] += x;
        __syncthreads();
    }
    if (t < 64) dhist[t] = (t == 0) ? 0 : part[t - 1];
    __syncthreads();
    if (t < nr) {
        int d = min(cnt128[t], 63);
        int sl = atomicAdd(&dhist[d], 1);
        slotOf[t] = sl;
        rowOf[sl] = t;
    }
    __syncthreads();

    // sorted-slot edge-count scan
    part[t] = (t < nr) ? cnt128[rowOf[t]] : 0;
    __syncthreads();
    for (int o = 1; o < SORT_T; o <<= 1) {
        int x = (t >= o) ? part[t - o] : 0;
        __syncthreads();
        part[t] += x;
        __syncthreads();
    }
    if (t < nr) offS[t] = (t == 0) ? 0 : part[t - 1];
    __syncthreads();

    if (t < nr) {
        startOut[rbase + t] = base + offS[t];
        origRow[rbase + t]  = rbase + rowOf[t];
        placeOff[t] = offS[slotOf[t]];
    }
    if (b == nbuck - 1 && t == 0) startOut[ntotal] = nnz;
    __syncthreads();

    // place 4B edges into slot order (contiguous ~6KB bucket window)
    for (int i = t; i < tot; i += SORT_T) {
        int p = atomicAdd(&placeOff[rbuf[i]], 1);
        edges[base + p] = buf[i];
    }
}

// fp32 -> fp16 table conversion, 4 elements/thread.
__global__ void conv_kernel(const float* __restrict__ in, __half* __restrict__ outh, int n4) {
    int i = blockIdx.x * blockDim.x + threadIdx.x;
    if (i >= n4) return;
    float4 v = ((const float4*)in)[i];
    __half2* o = (__half2*)outh;
    o[2 * i]     = __floats2half2_rn(v.x, v.y);
    o[2 * i + 1] = __floats2half2_rn(v.z, v.w);
}

// ---------- SpMM over degree-sorted slots, 4B packed edges ----------
// Wave = 4 slots; lane-group g (16 lanes, 4 dims/lane) owns slot 4w+g:
// 4 edges/iter, no cross-group reduction, full-width store.

__global__ void spmm_slot(const int* __restrict__ start, const int* __restrict__ origRow,
                          const unsigned* __restrict__ edges,
                          const __half* __restrict__ Ein, __half* __restrict__ Eout,
                          int nslots) {
    int t = blockIdx.x * blockDim.x + threadIdx.x;
    int w = t >> 6;
    int lane = t & 63;
    int g = lane >> 4, l = lane & 15;
    int s = 4 * w + g;
    if (s >= nslots) return;
    int b = start[s];
    int e = start[s + 1];
    int ro = origRow[s];
    float a0 = 0.f, a1 = 0.f, a2 = 0.f, a3 = 0.f;
    for (int k = b; k < e; k += 4) {
        unsigned ed[4];
#pragma unroll
        for (int j = 0; j < 4; j++) {
            int kk = k + j;
            ed[j] = (kk < e) ? edges[kk] : 0u;      // enc==0 -> w=0
        }
        ushort4 gv[4];
#pragma unroll
        for (int j = 0; j < 4; j++) {
            gv[j] = *(const ushort4*)(Ein + (size_t)(ed[j] & 0x3FFFFu) * LATENT + 4 * l);
        }
#pragma unroll
        for (int j = 0; j < 4; j++) {
            float wv = dec_val14(ed[j] >> 18);
            const __half2* h2 = (const __half2*)&gv[j];
            a0 += wv * __low2float(h2[0]);
            a1 += wv * __high2float(h2[0]);
            a2 += wv * __low2float(h2[1]);
            a3 += wv * __high2float(h2[1]);
        }
    }
    union { ushort4 u; __half2 h[2]; } o;
    o.h[0] = __floats2half2_rn(a0, a1);
    o.h[1] = __floats2half2_rn(a2, a3);
    *(ushort4*)(Eout + (size_t)ro * LATENT + 4 * l) = o.u;
}

// ---------- epilogue ----------

__global__ void finalize2(const int* __restrict__ users, const int* __restrict__ pos,
                          const int* __restrict__ neg, const float* __restrict__ E0,
                          const __half* __restrict__ E1, const __half* __restrict__ E2,
                          const __half* __restrict__ E3, float* __restrict__ out, int batch) {
    int t = blockIdx.x * blockDim.x + threadIdx.x;
    int total = 3 * batch * LATENT;
    if (t >= total) return;
    int d = t & 63;
    int b = t >> 6;
    int g = b / batch;
    int bb = b - g * batch;
    int r = (g == 0) ? users[bb] : (g == 1) ? (N_USERS_C + pos[bb]) : (N_USERS_C + neg[bb]);
    size_t idx = (size_t)r * LATENT + d;
    float e0 = E0[idx];
    float s = e0 + __half2float(E1[idx]) + __half2float(E2[idx]) + __half2float(E3[idx]);
    out[t] = 0.25f * s;
    out[total + t] = e0;
}

extern "C" void kernel_launch(void* const* d_in, const int* in_sizes, int n_in,
                              void* d_out, int out_size, void* d_ws, size_t ws_size,
                              hipStream_t stream) {
    const int*   users = (const int*)d_in[0];
    const int*   pos   = (const int*)d_in[1];
    const int*   neg   = (const int*)d_in[2];
    const float* E0    = (const float*)d_in[3];
    const int*   row   = (const int*)d_in[4];
    const int*   col   = (const int*)d_in[5];
    const float* vals  = (const float*)d_in[6];
    float*       out   = (float*)d_out;

    const int batch  = in_sizes[0];          // 4096
    const int nnz    = in_sizes[4];          // 1,200,000
    const int ntotal = in_sizes[3] / LATENT; // 150,000
    const int nbuck  = (ntotal + BROWS - 1) / BROWS;        // 1172
    const int nblkA  = (nnz + SORT_CHUNK - 1) / SORT_CHUNK; // 293

    auto align256 = [](size_t x) { return (x + 255) & ~(size_t)255; };

    const size_t hbufBytes = align256((size_t)ntotal * LATENT * sizeof(__half)); // 19.2 MB
    const size_t edgeBytes = align256((size_t)nnz * sizeof(unsigned));           // 4.8 MB
    const size_t auxBytes  = align256((size_t)nnz * sizeof(unsigned));           // 4.8 MB
    const size_t rlBytes   = align256((size_t)nnz);                              // 1.2 MB
    const size_t matBytes  = align256((size_t)nblkA * nbuck * sizeof(int));      // 1.38 MB
    const size_t stBytes   = align256((size_t)(ntotal + 1) * sizeof(int));
    const size_t bsBytes   = align256((size_t)(nbuck + 1) * sizeof(int));

    char* p = (char*)d_ws;
    __half* E0h     = (__half*)p;           p += hbufBytes;
    __half* bufA    = (__half*)p;           p += hbufBytes;   // E1
    __half* bufB    = (__half*)p;           p += hbufBytes;   // E2 (cntmat/srcmat alias: build-only)
    __half* bufC    = (__half*)p;           p += hbufBytes;   // E3 (aux/rowloc alias: build-only)
    unsigned* edges = (unsigned*)p;         p += edgeBytes;   // final 4B packed edges
    int*    startA  = (int*)p;              p += stBytes;
    int*    origRow = (int*)p;              p += stBytes;
    int*    bstart  = (int*)p;              p += bsBytes;
    int*    bcnt    = (int*)p;              p += bsBytes;
    // aliases (consumed before their host buffers are first written):
    unsigned*      aux    = (unsigned*)bufC;                    // bufC written at layer 3
    unsigned char* rowloc = (unsigned char*)((char*)bufC + auxBytes);
    int* cntmat = (int*)bufB;                                   // bufB written at layer 2
    int* srcmat = (int*)((char*)bufB + matBytes);

    hipMemsetAsync(bcnt, 0, (size_t)nbuck * sizeof(int), stream);

    const int threads = 256;
    const int slotWaves = (ntotal + 3) / 4;                        // 37500
    const int spBlocks = (slotWaves * 64 + threads - 1) / threads; // 9375
    const int gBlocks = (3 * batch * LATENT + threads - 1) / threads;
    const int n4 = ntotal * LATENT / 4;
    const int cBlocks = (n4 + threads - 1) / threads;

    // Build degree-sorted packed CSR
    sortA_kernel<<<nblkA, SORT_T, 0, stream>>>(row, col, vals, aux, rowloc,
                                               cntmat, srcmat, bcnt, nnz, nbuck);
    bscan_kernel<<<1, SORT_T, 0, stream>>>(bcnt, bstart, nbuck);
    conv_kernel<<<cBlocks, threads, 0, stream>>>(E0, E0h, n4);   // independent; fills gap
    sortB_kernel<<<nbuck, SORT_T, 0, stream>>>(aux, rowloc, cntmat, srcmat, bstart,
                                               edges, startA, origRow,
                                               nblkA, nbuck, ntotal, nnz);

    // Three SpMM layers
    spmm_slot<<<spBlocks, threads, 0, stream>>>(startA, origRow, edges, E0h, bufA, ntotal);
    spmm_slot<<<spBlocks, threads, 0, stream>>>(startA, origRow, edges, bufA, bufB, ntotal);
    spmm_slot<<<spBlocks, threads, 0, stream>>>(startA, origRow, edges, bufB, bufC, ntotal);

    finalize2<<<gBlocks, threads, 0, stream>>>(users, pos, neg, E0, bufA, bufB, bufC, out, batch);
}

// Round 13
// 204.733 us; speedup vs baseline: 7.3211x; 1.1368x over previous
//
#include <hip/hip_runtime.h>
#include <hip/hip_fp16.h>

#define LATENT 64
#define N_USERS_C 100000

#define BROWS 128
#define LOG_BROWS 7
#define NBUCK_MAX 1280         // >= ceil(150000/128) = 1172
#define NBLKA_MAX 512          // >= ceil(nnz/4096) = 293
#define SORT_T 256
#define SORT_E 16
#define SORT_CHUNK (SORT_T * SORT_E)   // 4096 edges per block
#define BUCK_CAP 4608          // max edges per 128-row bucket (item-bucket mean ~1536)

// Edge payload: col:18 | val-e4m10:14  (exp bias 0x77 -> covers 2^-8..2^7;
// vals in [0.022, 1.0]; enc==0 reserved for "zero weight").
__device__ __forceinline__ unsigned enc_val14(float v) {
    unsigned vb = (unsigned)__float_as_int(v) + 0x1000u;            // round to nearest
    return (((vb >> 23) - 0x77u) << 10) | ((vb >> 13) & 0x3FFu);    // 14 bits
}
__device__ __forceinline__ float dec_val14(unsigned m) {
    return __uint_as_float(m ? ((((m >> 10) + 0x77u) << 23) | ((m & 0x3FFu) << 13)) : 0u);
}

// ---------- Phase A: per-block LDS bucket sort, fully-coalesced output ----------

__global__ void sortA_kernel(const int* __restrict__ row, const int* __restrict__ col,
                             const float* __restrict__ vals,
                             unsigned* __restrict__ aux, unsigned char* __restrict__ rowloc,
                             int* __restrict__ cntmat, int* __restrict__ srcmat,
                             int* __restrict__ bcnt, int nnz, int nbuck) {
    __shared__ int cnt[NBUCK_MAX];
    __shared__ int off[NBUCK_MAX];
    __shared__ int part[SORT_T];
    __shared__ unsigned buf[SORT_CHUNK];        // 16 KB
    __shared__ unsigned char rbuf[SORT_CHUNK];  // 4 KB
    int t = threadIdx.x, blk = blockIdx.x;
    int base = blk * SORT_CHUNK;

    for (int i = t; i < nbuck; i += SORT_T) cnt[i] = 0;
    __syncthreads();

    int      eb[SORT_E];
    unsigned pl[SORT_E];
    unsigned char rl8[SORT_E];
#pragma unroll
    for (int j = 0; j < SORT_E; j++) {
        int e = base + j * SORT_T + t;
        if (e < nnz) {
            int r = row[e];
            int b = r >> LOG_BROWS;
            eb[j] = b;
            pl[j] = (unsigned)col[e] | (enc_val14(vals[e]) << 18);
            rl8[j] = (unsigned char)(r & (BROWS - 1));
            atomicAdd(&cnt[b], 1);
        } else {
            eb[j] = -1;
        }
    }
    __syncthreads();

    int chunk = (nbuck + SORT_T - 1) / SORT_T;
    int lo = t * chunk, hi = lo + chunk; if (hi > nbuck) hi = nbuck;
    int s = 0;
    for (int i = lo; i < hi; i++) s += cnt[i];
    part[t] = s;
    __syncthreads();
    for (int o = 1; o < SORT_T; o <<= 1) {
        int x = (t >= o) ? part[t - o] : 0;
        __syncthreads();
        part[t] += x;
        __syncthreads();
    }
    int run = (t == 0) ? 0 : part[t - 1];
    for (int i = lo; i < hi; i++) { off[i] = run; run += cnt[i]; }
    __syncthreads();

#pragma unroll
    for (int j = 0; j < SORT_E; j++) {
        if (eb[j] >= 0) {
            int p = atomicAdd(&off[eb[j]], 1);
            buf[p] = pl[j];
            rbuf[p] = rl8[j];
        }
    }
    __syncthreads();

    for (int b = t; b < nbuck; b += SORT_T) {
        int c = cnt[b];
        int beg = off[b] - c;
        cntmat[(size_t)blk * nbuck + b] = c;
        srcmat[(size_t)blk * nbuck + b] = beg;
        if (c) atomicAdd(&bcnt[b], c);
    }
    int nvalid = nnz - base; if (nvalid > SORT_CHUNK) nvalid = SORT_CHUNK;
    for (int i = t; i < nvalid; i += SORT_T) {
        aux[base + i] = buf[i];
        rowloc[base + i] = rbuf[i];
    }
}

// ---------- bucket-start exclusive scan (single block) ----------

__global__ void bscan_kernel(const int* __restrict__ bcnt, int* __restrict__ bstart,
                             int nbuck) {
    __shared__ int part[SORT_T];
    int t = threadIdx.x;
    int chunk = (nbuck + SORT_T - 1) / SORT_T;
    int lo = t * chunk, hi = lo + chunk; if (hi > nbuck) hi = nbuck;
    int s = 0;
    for (int i = lo; i < hi; i++) s += bcnt[i];
    part[t] = s;
    __syncthreads();
    for (int o = 1; o < SORT_T; o <<= 1) {
        int x = (t >= o) ? part[t - o] : 0;
        __syncthreads();
        part[t] += x;
        __syncthreads();
    }
    int run = (t == 0) ? 0 : part[t - 1];
    for (int i = lo; i < hi; i++) { bstart[i] = run; run += bcnt[i]; }
    if (t == SORT_T - 1) bstart[nbuck] = run;   // = nnz
}

// ---------- Phase B: bucket -> degree-sorted-slot CSR (+ row->slot map) ----------

__global__ void sortB_kernel(const unsigned* __restrict__ aux,
                             const unsigned char* __restrict__ rowloc,
                             const int* __restrict__ cntmat, const int* __restrict__ srcmat,
                             const int* __restrict__ bstart,
                             unsigned* __restrict__ edges, int* __restrict__ startOut,
                             int* __restrict__ origRow, int* __restrict__ slotOfRow,
                             int nblkA, int nbuck, int ntotal, int nnz) {
    __shared__ int rs[NBLKA_MAX], roff[NBLKA_MAX + 1];
    __shared__ int part[SORT_T];
    __shared__ unsigned buf[BUCK_CAP];          // 18.4 KB
    __shared__ unsigned char rbuf[BUCK_CAP];    // 4.6 KB
    __shared__ int cnt128[BROWS];
    __shared__ int slotOf[BROWS];
    __shared__ int rowOf[BROWS];
    __shared__ int offS[BROWS];
    __shared__ int placeOff[BROWS];
    __shared__ int dhist[64];
    int b = blockIdx.x, t = threadIdx.x;
    int base = bstart[b];
    int tot = bstart[b + 1] - base;
    int rbase = b * BROWS;
    int nr = ntotal - rbase; if (nr > BROWS) nr = BROWS;

    int chunk = (nblkA + SORT_T - 1) / SORT_T;
    int lo = t * chunk, hi = lo + chunk; if (hi > nblkA) hi = nblkA;
    int rcl[8];
    int s = 0;
    for (int i = lo; i < hi; i++) {
        int c = cntmat[(size_t)i * nbuck + b];
        rcl[i - lo] = c;
        rs[i] = srcmat[(size_t)i * nbuck + b];
        s += c;
    }
    part[t] = s;
    if (t < BROWS) cnt128[t] = 0;
    if (t < 64) dhist[t] = 0;
    __syncthreads();
    for (int o = 1; o < SORT_T; o <<= 1) {
        int x = (t >= o) ? part[t - o] : 0;
        __syncthreads();
        part[t] += x;
        __syncthreads();
    }
    int run = (t == 0) ? 0 : part[t - 1];
    for (int i = lo; i < hi; i++) { roff[i] = run; run += rcl[i - lo]; }
    if (t == SORT_T - 1) roff[nblkA] = part[SORT_T - 1];
    __syncthreads();

    // coalesced gather: edge i -> binary search run (largest with roff[r] <= i)
    for (int i = t; i < tot; i += SORT_T) {
        int lo2 = 0, hi2 = nblkA;
        while (hi2 - lo2 > 1) {
            int mid = (lo2 + hi2) >> 1;
            if (roff[mid] <= i) lo2 = mid; else hi2 = mid;
        }
        size_t src = (size_t)lo2 * SORT_CHUNK + rs[lo2] + (i - roff[lo2]);
        buf[i] = aux[src];
        unsigned char rl = rowloc[src];
        rbuf[i] = rl;
        atomicAdd(&cnt128[rl], 1);
    }
    __syncthreads();

    if (t < nr) { int d = min(cnt128[t], 63); atomicAdd(&dhist[d], 1); }
    __syncthreads();
    part[t] = (t < 64) ? dhist[t] : 0;
    __syncthreads();
    for (int o = 1; o < 64; o <<= 1) {
        int x = (t >= o) ? part[t - o] : 0;
        __syncthreads();
        part[t] += x;
        __syncthreads();
    }
    if (t < 64) dhist[t] = (t == 0) ? 0 : part[t - 1];
    __syncthreads();
    if (t < nr) {
        int d = min(cnt128[t], 63);
        int sl = atomicAdd(&dhist[d], 1);
        slotOf[t] = sl;
        rowOf[sl] = t;
    }
    __syncthreads();

    part[t] = (t < nr) ? cnt128[rowOf[t]] : 0;
    __syncthreads();
    for (int o = 1; o < SORT_T; o <<= 1) {
        int x = (t >= o) ? part[t - o] : 0;
        __syncthreads();
        part[t] += x;
        __syncthreads();
    }
    if (t < nr) offS[t] = (t == 0) ? 0 : part[t - 1];
    __syncthreads();

    if (t < nr) {
        startOut[rbase + t]   = base + offS[t];
        origRow[rbase + t]    = rbase + rowOf[t];
        slotOfRow[rbase + t]  = rbase + slotOf[t];   // row -> global slot (for fused L3)
        placeOff[t] = offS[slotOf[t]];
    }
    if (b == nbuck - 1 && t == 0) startOut[ntotal] = nnz;
    __syncthreads();

    for (int i = t; i < tot; i += SORT_T) {
        int p = atomicAdd(&placeOff[rbuf[i]], 1);
        edges[base + p] = buf[i];
    }
}

// fp32 -> fp16 table conversion, 4 elements/thread.
__global__ void conv_kernel(const float* __restrict__ in, __half* __restrict__ outh, int n4) {
    int i = blockIdx.x * blockDim.x + threadIdx.x;
    if (i >= n4) return;
    float4 v = ((const float4*)in)[i];
    __half2* o = (__half2*)outh;
    o[2 * i]     = __floats2half2_rn(v.x, v.y);
    o[2 * i + 1] = __floats2half2_rn(v.z, v.w);
}

// ---------- SpMM over degree-sorted slots, 4B packed edges (layers 1-2) ----------

__global__ void spmm_slot(const int* __restrict__ start, const int* __restrict__ origRow,
                          const unsigned* __restrict__ edges,
                          const __half* __restrict__ Ein, __half* __restrict__ Eout,
                          int nslots) {
    int t = blockIdx.x * blockDim.x + threadIdx.x;
    int w = t >> 6;
    int lane = t & 63;
    int g = lane >> 4, l = lane & 15;
    int s = 4 * w + g;
    if (s >= nslots) return;
    int b = start[s];
    int e = start[s + 1];
    int ro = origRow[s];
    float a0 = 0.f, a1 = 0.f, a2 = 0.f, a3 = 0.f;
    for (int k = b; k < e; k += 4) {
        unsigned ed[4];
#pragma unroll
        for (int j = 0; j < 4; j++) {
            int kk = k + j;
            ed[j] = (kk < e) ? edges[kk] : 0u;      // enc==0 -> w=0
        }
        ushort4 gv[4];
#pragma unroll
        for (int j = 0; j < 4; j++) {
            gv[j] = *(const ushort4*)(Ein + (size_t)(ed[j] & 0x3FFFFu) * LATENT + 4 * l);
        }
#pragma unroll
        for (int j = 0; j < 4; j++) {
            float wv = dec_val14(ed[j] >> 18);
            const __half2* h2 = (const __half2*)&gv[j];
            a0 += wv * __low2float(h2[0]);
            a1 += wv * __high2float(h2[0]);
            a2 += wv * __low2float(h2[1]);
            a3 += wv * __high2float(h2[1]);
        }
    }
    union { ushort4 u; __half2 h[2]; } o;
    o.h[0] = __floats2half2_rn(a0, a1);
    o.h[1] = __floats2half2_rn(a2, a3);
    *(ushort4*)(Eout + (size_t)ro * LATENT + 4 * l) = o.u;
}

// ---------- Fused layer-3 + finalize ----------
// E3 is only consumed at the 12288 batch rows, so layer 3 runs per OUTPUT
// ENTRY (on-the-fly E2 gathers) instead of all 150K rows (~12x less work).
// Wave = 4 entries; lane-group g (16 lanes, 4 dims/lane) owns entry 4w+g.

__global__ void fin_fused(const int* __restrict__ users, const int* __restrict__ pos,
                          const int* __restrict__ neg,
                          const int* __restrict__ start, const int* __restrict__ slotOfRow,
                          const unsigned* __restrict__ edges,
                          const float* __restrict__ E0, const __half* __restrict__ E1,
                          const __half* __restrict__ E2,
                          float* __restrict__ out, int batch) {
    int t = blockIdx.x * blockDim.x + threadIdx.x;
    int w = t >> 6;
    int lane = t & 63;
    int g = lane >> 4, l = lane & 15;
    int i = 4 * w + g;                  // output entry 0..3*batch
    int nent = 3 * batch;
    if (i >= nent) return;
    int grp = i / batch;
    int bb = i - grp * batch;
    int r = (grp == 0) ? users[bb] : (grp == 1) ? (N_USERS_C + pos[bb]) : (N_USERS_C + neg[bb]);
    int s = slotOfRow[r];
    int b = start[s];
    int e = start[s + 1];
    float a0 = 0.f, a1 = 0.f, a2 = 0.f, a3 = 0.f;
    for (int k = b; k < e; k += 4) {
        unsigned ed[4];
#pragma unroll
        for (int j = 0; j < 4; j++) {
            int kk = k + j;
            ed[j] = (kk < e) ? edges[kk] : 0u;
        }
        ushort4 gv[4];
#pragma unroll
        for (int j = 0; j < 4; j++) {
            gv[j] = *(const ushort4*)(E2 + (size_t)(ed[j] & 0x3FFFFu) * LATENT + 4 * l);
        }
#pragma unroll
        for (int j = 0; j < 4; j++) {
            float wv = dec_val14(ed[j] >> 18);
            const __half2* h2 = (const __half2*)&gv[j];
            a0 += wv * __low2float(h2[0]);
            a1 += wv * __high2float(h2[0]);
            a2 += wv * __low2float(h2[1]);
            a3 += wv * __high2float(h2[1]);
        }
    }
    size_t idx = (size_t)r * LATENT + 4 * l;
    float4 e0v = *(const float4*)(E0 + idx);
    ushort4 e1u = *(const ushort4*)(E1 + idx);
    ushort4 e2u = *(const ushort4*)(E2 + idx);
    const __half2* h1 = (const __half2*)&e1u;
    const __half2* h2v = (const __half2*)&e2u;
    float4 res;
    res.x = 0.25f * (e0v.x + __low2float(h1[0])  + __low2float(h2v[0])  + a0);
    res.y = 0.25f * (e0v.y + __high2float(h1[0]) + __high2float(h2v[0]) + a1);
    res.z = 0.25f * (e0v.z + __low2float(h1[1])  + __low2float(h2v[1])  + a2);
    res.w = 0.25f * (e0v.w + __high2float(h1[1]) + __high2float(h2v[1]) + a3);
    int total = nent * LATENT;
    *(float4*)(out + (size_t)i * LATENT + 4 * l) = res;
    *(float4*)(out + total + (size_t)i * LATENT + 4 * l) = e0v;
}

extern "C" void kernel_launch(void* const* d_in, const int* in_sizes, int n_in,
                              void* d_out, int out_size, void* d_ws, size_t ws_size,
                              hipStream_t stream) {
    const int*   users = (const int*)d_in[0];
    const int*   pos   = (const int*)d_in[1];
    const int*   neg   = (const int*)d_in[2];
    const float* E0    = (const float*)d_in[3];
    const int*   row   = (const int*)d_in[4];
    const int*   col   = (const int*)d_in[5];
    const float* vals  = (const float*)d_in[6];
    float*       out   = (float*)d_out;

    const int batch  = in_sizes[0];          // 4096
    const int nnz    = in_sizes[4];          // 1,200,000
    const int ntotal = in_sizes[3] / LATENT; // 150,000
    const int nbuck  = (ntotal + BROWS - 1) / BROWS;        // 1172
    const int nblkA  = (nnz + SORT_CHUNK - 1) / SORT_CHUNK; // 293

    auto align256 = [](size_t x) { return (x + 255) & ~(size_t)255; };

    const size_t hbufBytes = align256((size_t)ntotal * LATENT * sizeof(__half)); // 19.2 MB
    const size_t edgeBytes = align256((size_t)nnz * sizeof(unsigned));           // 4.8 MB
    const size_t auxBytes  = align256((size_t)nnz * sizeof(unsigned));           // 4.8 MB
    const size_t matBytes  = align256((size_t)nblkA * nbuck * sizeof(int));      // 1.38 MB
    const size_t stBytes   = align256((size_t)(ntotal + 1) * sizeof(int));
    const size_t bsBytes   = align256((size_t)(nbuck + 1) * sizeof(int));

    char* p = (char*)d_ws;
    __half* E0h      = (__half*)p;          p += hbufBytes;
    __half* bufA     = (__half*)p;          p += hbufBytes;   // E1
    __half* bufB     = (__half*)p;          p += hbufBytes;   // E2 (cntmat/srcmat alias: build-only)
    __half* bufC     = (__half*)p;          p += hbufBytes;   // (aux/rowloc alias: build-only; no E3 anymore)
    unsigned* edges  = (unsigned*)p;        p += edgeBytes;   // final 4B packed edges
    int*    startA   = (int*)p;             p += stBytes;
    int*    origRow  = (int*)p;             p += stBytes;
    int*    slotOfRw = (int*)p;             p += stBytes;
    int*    bstart   = (int*)p;             p += bsBytes;
    int*    bcnt     = (int*)p;             p += bsBytes;
    // aliases (consumed before their host buffers are first written):
    unsigned*      aux    = (unsigned*)bufC;
    unsigned char* rowloc = (unsigned char*)((char*)bufC + auxBytes);
    int* cntmat = (int*)bufB;                                   // bufB written at layer 2
    int* srcmat = (int*)((char*)bufB + matBytes);

    hipMemsetAsync(bcnt, 0, (size_t)nbuck * sizeof(int), stream);

    const int threads = 256;
    const int slotWaves = (ntotal + 3) / 4;                        // 37500
    const int spBlocks = (slotWaves * 64 + threads - 1) / threads; // 9375
    const int nent = 3 * batch;                                    // 12288
    const int fBlocks = (((nent + 3) / 4) * 64 + threads - 1) / threads; // 768
    const int n4 = ntotal * LATENT / 4;
    const int cBlocks = (n4 + threads - 1) / threads;

    // Build degree-sorted packed CSR
    sortA_kernel<<<nblkA, SORT_T, 0, stream>>>(row, col, vals, aux, rowloc,
                                               cntmat, srcmat, bcnt, nnz, nbuck);
    bscan_kernel<<<1, SORT_T, 0, stream>>>(bcnt, bstart, nbuck);
    conv_kernel<<<cBlocks, threads, 0, stream>>>(E0, E0h, n4);   // independent; fills gap
    sortB_kernel<<<nbuck, SORT_T, 0, stream>>>(aux, rowloc, cntmat, srcmat, bstart,
                                               edges, startA, origRow, slotOfRw,
                                               nblkA, nbuck, ntotal, nnz);

    // Layers 1-2 full; layer 3 fused into finalize (batch rows only)
    spmm_slot<<<spBlocks, threads, 0, stream>>>(startA, origRow, edges, E0h, bufA, ntotal);
    spmm_slot<<<spBlocks, threads, 0, stream>>>(startA, origRow, edges, bufA, bufB, ntotal);
    fin_fused<<<fBlocks, threads, 0, stream>>>(users, pos, neg, startA, slotOfRw, edges,
                                               E0, bufA, bufB, out, batch);
}